// Round 3
// baseline (368.725 us; speedup 1.0000x reference)
//
#include <hip/hip_runtime.h>
#include <hip/hip_bf16.h>
#include <cstdint>
#include <cstddef>

#define BB   4
#define SS   2048
#define HIDD 1024
#define NHH  16
#define HDD  64
#define MM   (BB*SS)   // 8192
#define L2E  1.4426950408889634f
#define SH4  5.770780163555854f   // 4 * L2E

typedef __bf16    bf16x8 __attribute__((ext_vector_type(8)));
typedef float     f32x4  __attribute__((ext_vector_type(4)));
typedef _Float16  half4  __attribute__((ext_vector_type(4)));
typedef _Float16  half8  __attribute__((ext_vector_type(8)));
typedef _Float16  half2v __attribute__((ext_vector_type(2)));
typedef unsigned  u32x4  __attribute__((ext_vector_type(4)));

__device__ __forceinline__ unsigned short f2b(float f) {
    unsigned u = __builtin_bit_cast(unsigned, f);
    return (unsigned short)((u + 0x7FFFu + ((u >> 16) & 1u)) >> 16);
}

__device__ __forceinline__ half2v pkrtz(float a, float b) {
    return __builtin_bit_cast(half2v, __builtin_amdgcn_cvt_pkrtz(a, b));
}

__device__ __forceinline__ unsigned pkrtz_u(float a, float b) {
    return __builtin_bit_cast(unsigned, __builtin_amdgcn_cvt_pkrtz(a, b));
}

// async global->LDS, 16B per lane. LDS dest must be wave-uniform base + lane*16.
__device__ __forceinline__ void gl_lds16(const void* g, void* l) {
    __builtin_amdgcn_global_load_lds(
        (const __attribute__((address_space(1))) void*)g,
        (__attribute__((address_space(3))) void*)l, 16, 0, 0);
}

// ---------------------------------------------------------------- fp32 -> bf16 (all 4 srcs)
#define NX4 (MM * HIDD / 4)
#define NW4 (HIDD * HIDD / 4)   // 262144 = 2^18
__global__ __launch_bounds__(256) void cvt_all(
    const float* __restrict__ x,  const float* __restrict__ wq,
    const float* __restrict__ wk, const float* __restrict__ wv,
    unsigned short* __restrict__ xb, unsigned short* __restrict__ wb)
{
    int i = blockIdx.x * 256 + threadIdx.x;
    const float* src; unsigned short* dst; int off;
    if (i < NX4) { src = x; dst = xb; off = i; }
    else {
        int j = i - NX4;
        int w = j >> 18;          // 0,1,2
        off = j & (NW4 - 1);
        src = (w == 0) ? wq : (w == 1) ? wk : wv;
        dst = wb + (size_t)w * HIDD * HIDD;
    }
    float4 v = reinterpret_cast<const float4*>(src)[off];
    ushort4 o;
    o.x = f2b(v.x); o.y = f2b(v.y); o.z = f2b(v.z); o.w = f2b(v.w);
    reinterpret_cast<ushort4*>(dst)[off] = o;
}

// ---------------------------------------------------------------- QKV GEMM
// C = x @ W^T + b. grid (64 m-tiles [fastest -> XCD = m%8], 24 = op*8 + n-tile).
// BK=64, XOR-swizzled LDS (row stride 64 elems; 16B group g ^= row&7).
// Operand roles per op:
//   op==2 (V): A = x-tile (rows m), B = W-tile (rows n) -> C rows = s  -> half4 V^T stores
//   op<2 (Q,K): A = W-tile (rows n), B = x-tile (rows m) -> C rows = d -> ushort4 stores
// Q,K written bf16 [B,NH,S,HD]; V written f16 transposed [B,NH,HD,S].
// Q pre-scaled by 0.125*log2(e) (folds softmax scale AND exp->exp2 conversion).
__global__ __launch_bounds__(256, 3) void qkv_gemm(
    const unsigned short* __restrict__ xb,
    const unsigned short* __restrict__ wb,
    const float* __restrict__ bq, const float* __restrict__ bk, const float* __restrict__ bv,
    unsigned short* __restrict__ Qb, unsigned short* __restrict__ Kb,
    _Float16* __restrict__ Vtb)
{
    __shared__ unsigned short lA[128 * 64];  // x-tile, 16 KB
    __shared__ unsigned short lB[128 * 64];  // W-tile, 16 KB

    const int tid  = threadIdx.x;
    const int wave = tid >> 6, lane = tid & 63;
    const int lh   = lane & 15, quad = lane >> 4;
    const int l7   = lh & 7;
    const int m0   = blockIdx.x * 128;
    const int opn  = blockIdx.y;
    const int op   = opn >> 3;            // 0=Q 1=K 2=V
    const int n0   = (opn & 7) * 128;
    const unsigned short* W = wb + (size_t)op * HIDD * HIDD;
    const float* bias = (op == 0) ? bq : (op == 1) ? bk : bv;

    f32x4 acc[4][4];
#pragma unroll
    for (int i = 0; i < 4; i++)
#pragma unroll
        for (int j = 0; j < 4; j++) acc[i][j] = f32x4{0.f, 0.f, 0.f, 0.f};

    const int wm = wave & 1, wn = wave >> 1;
    // A/B operand sources (wave-uniform)
    const unsigned short* srcA = (op == 2) ? lA : lB;
    const unsigned short* srcB = (op == 2) ? lB : lA;
    const int offA = (op == 2) ? wm : wn;
    const int offB = (op == 2) ? wn : wm;

    const int srow = tid >> 3;        // 0..31
    const int sg   = tid & 7;         // 16B group 0..7

    for (int k0 = 0; k0 < HIDD; k0 += 64) {
#pragma unroll
        for (int rr = 0; rr < 4; rr++) {
            const int row = srow + rr * 32;
            const int gcol = k0 + ((sg ^ (row & 7)) << 3);
            gl_lds16(&xb[(size_t)(m0 + row) * HIDD + gcol], &lA[row * 64 + sg * 8]);
            gl_lds16(&W [(size_t)(n0 + row) * HIDD + gcol], &lB[row * 64 + sg * 8]);
        }
        __syncthreads();

#pragma unroll
        for (int kk = 0; kk < 2; kk++) {
            bf16x8 aF[4], bF[4];
#pragma unroll
            for (int i = 0; i < 4; i++) {
                const int row = offA * 64 + i * 16 + lh;
                aF[i] = *reinterpret_cast<const bf16x8*>(
                    &srcA[row * 64 + (((kk * 4 + quad) ^ l7) << 3)]);
            }
#pragma unroll
            for (int j = 0; j < 4; j++) {
                const int row = offB * 64 + j * 16 + lh;
                bF[j] = *reinterpret_cast<const bf16x8*>(
                    &srcB[row * 64 + (((kk * 4 + quad) ^ l7) << 3)]);
            }
#pragma unroll
            for (int i = 0; i < 4; i++)
#pragma unroll
                for (int j = 0; j < 4; j++)
                    acc[i][j] = __builtin_amdgcn_mfma_f32_16x16x32_bf16(aF[i], bF[j], acc[i][j], 0, 0, 0);
        }
        __syncthreads();
    }

    // epilogue: C/D layout col = lane&15, row = quad*4 + reg
    if (op == 2) {
        // rows = m (s), cols = n (d): V^T[d][s], 4 consecutive s per lane -> half4
#pragma unroll
        for (int j = 0; j < 4; j++) {
            const int n = n0 + offB * 64 + j * 16 + lh;
            const float bvv = bias[n];
            const int h = n >> 6, d = n & 63;
#pragma unroll
            for (int i = 0; i < 4; i++) {
                const int mrow = m0 + offA * 64 + i * 16 + quad * 4;
                const int b_ = mrow >> 11, s_ = mrow & 2047;
                half2v h01 = pkrtz(acc[i][j][0] + bvv, acc[i][j][1] + bvv);
                half2v h23 = pkrtz(acc[i][j][2] + bvv, acc[i][j][3] + bvv);
                half4 hv; hv[0] = h01[0]; hv[1] = h01[1]; hv[2] = h23[0]; hv[3] = h23[1];
                size_t a = ((size_t)(b_ * NHH + h) * HDD + d) * SS + s_;
                *reinterpret_cast<half4*>(&Vtb[a]) = hv;
            }
        }
    } else {
        // rows = n (d), cols = m (s): Q/K[s][d], 4 consecutive d per lane -> ushort4
        const float qs = (op == 0) ? (0.125f * L2E) : 1.0f;
        unsigned short* dst = (op == 0) ? Qb : Kb;
#pragma unroll
        for (int i = 0; i < 4; i++) {
            const int nb = n0 + offA * 64 + i * 16 + quad * 4;
            const float4 bb = *reinterpret_cast<const float4*>(&bias[nb]);
            const int h = nb >> 6, d = nb & 63;
#pragma unroll
            for (int j = 0; j < 4; j++) {
                const int m = m0 + offB * 64 + j * 16 + lh;
                const int b_ = m >> 11, s_ = m & 2047;
                ushort4 o;
                o.x = f2b((acc[i][j][0] + bb.x) * qs);
                o.y = f2b((acc[i][j][1] + bb.y) * qs);
                o.z = f2b((acc[i][j][2] + bb.z) * qs);
                o.w = f2b((acc[i][j][3] + bb.w) * qs);
                *reinterpret_cast<ushort4*>(
                    &dst[((size_t)(b_ * NHH + h) * SS + s_) * HDD + d]) = o;
            }
        }
    }
}

// ---------------------------------------------------------------- flash attention
// grid (64 = b*NH+h [fastest -> all q-tiles of a head on one XCD], 16 q-tiles).
// 256 threads, q-tile 128 (32 q per wave). kt tile 64 keys.
// S^T = K*Q^T with PERMUTED key rows: QK MFMA (t,a) loads A-row lh with key
//   t*32 + 8*(lh>>2) + 4a + (lh&3)
// so its C output row (quad*4+r) holds key t*32 + quad*8 + 4a + r -> a=0/a=1
// concatenated form exactly the K=32 16x16x32 f16 PV B-operand in-register.
// R3: CROSS-TILE PIPELINE. Each barrier-free region runs
//   phaseA(kt+1) [QK MFMA + exp2 chains]  ||  phaseB(kt) [pure PV MFMA]
// so the matrix pipe is fed while exp2 chains resolve (R2 had both pipes at
// 43% = serialized phases). Enablers:
//  - K staged 2 tiles ahead via global_load_lds (2 buffers, parity-disjoint)
//  - V read straight from global into regs per wave (L2-resident: 4MB K+V per
//    XCD; each wave's 8 dwordx4 fully consume their 128B lines) -> no V-LDS
//    race, LDS = 24KB
//  - pf double-buffered as two NAMED arrays, x2-unrolled loop (static indexing)
//  - row-sum back on VALU (MFMA is now the bound pipe; -4 MFMA/kt, -8 VGPR)
//  - launch_bounds(256,3): VGPR<=168, no spills; 12 waves/CU ~= measured occ.
__global__ __launch_bounds__(256, 3) void attn_kernel(
    const unsigned short* __restrict__ Qb,
    const unsigned short* __restrict__ Kb,
    const _Float16* __restrict__ Vtb,
    const float* __restrict__ mask,
    float* __restrict__ out)
{
    __shared__ unsigned short lK[2][64 * 64];  // keys x d, swizzled (bits 0,1,3); 8 KB each
    __shared__ float         lmm[SS];          // mask*L2E - SH4, per key; 8 KB

    const int tid  = threadIdx.x;
    const int wave = tid >> 6, lane = tid & 63;
    const int lh   = lane & 15, quad = lane >> 4;
    const int l7   = lh & 7;
    const int bh = blockIdx.x, qt = blockIdx.y;
    const int b = bh >> 4, h = bh & 15;
    const unsigned short* Qh = Qb  + (size_t)bh * SS * HDD;
    const unsigned short* Kh = Kb  + (size_t)bh * SS * HDD;
    const _Float16*       Vh = Vtb + (size_t)bh * HDD * SS;
    const float* mk = mask + (size_t)b * SS;
    const int q0 = qt * 128;

    // Q fragments (B-operand): q = q0 + wave*32 + i*16 + lh, d = kk*32 + quad*8
    bf16x8 qF[2][2];
#pragma unroll
    for (int i = 0; i < 2; i++)
#pragma unroll
        for (int kk = 0; kk < 2; kk++)
            qF[i][kk] = *reinterpret_cast<const bf16x8*>(
                &Qh[(size_t)(q0 + wave * 32 + i * 16 + lh) * HDD + kk * 32 + quad * 8]);

    f32x4 oacc[2][4];
#pragma unroll
    for (int i = 0; i < 2; i++)
#pragma unroll
        for (int dj = 0; dj < 4; dj++) oacc[i][dj] = f32x4{0.f, 0.f, 0.f, 0.f};
    float ls[2] = {0.f, 0.f};

    const int srow = tid >> 3;        // 0..31
    const int sg   = tid & 7;

#define STAGE_K(KT, BUF) do {                                                  \
    const int kb_ = (KT) * 64;                                                 \
    _Pragma("unroll")                                                          \
    for (int rr = 0; rr < 2; rr++) {                                           \
        const int row = srow + rr * 32;                                        \
        const int swk = ((sg ^ ((row & 3) | ((row >> 1) & 4))) << 3);          \
        gl_lds16(&Kh[(size_t)(kb_ + row) * HDD + swk], &lK[BUF][row * 64 + sg * 8]); \
    }                                                                          \
} while (0)

#define PHASE_A(KT, PF) do {                                                   \
    const int bufA = (KT) & 1;                                                 \
    const int kbA  = (KT) * 64;                                                \
    _Pragma("unroll")                                                          \
    for (int t = 0; t < 2; t++) {                                              \
        _Pragma("unroll")                                                      \
        for (int a = 0; a < 2; a++) {                                          \
            const int key = t * 32 + ((lh & 12) << 1) + (a << 2) + (lh & 3);   \
            const int krow = key * 64;                                         \
            bf16x8 kf0 = *reinterpret_cast<const bf16x8*>(                     \
                &lK[bufA][krow + ((quad ^ l7) << 3)]);                         \
            bf16x8 kf1 = *reinterpret_cast<const bf16x8*>(                     \
                &lK[bufA][krow + (((4 + quad) ^ l7) << 3)]);                   \
            const f32x4 mm = *reinterpret_cast<const f32x4*>(                  \
                &lmm[kbA + t * 32 + quad * 8 + a * 4]);                        \
            _Pragma("unroll")                                                  \
            for (int i = 0; i < 2; i++) {                                      \
                f32x4 s = __builtin_amdgcn_mfma_f32_16x16x32_bf16(kf0, qF[i][0], mm, 0, 0, 0); \
                s = __builtin_amdgcn_mfma_f32_16x16x32_bf16(kf1, qF[i][1], s, 0, 0, 0);        \
                float e0 = __builtin_amdgcn_exp2f(s[0]);                       \
                float e1 = __builtin_amdgcn_exp2f(s[1]);                       \
                float e2 = __builtin_amdgcn_exp2f(s[2]);                       \
                float e3 = __builtin_amdgcn_exp2f(s[3]);                       \
                ls[i] += (e0 + e1) + (e2 + e3);                                \
                PF[t][i][a * 2 + 0] = pkrtz_u(e0, e1);                         \
                PF[t][i][a * 2 + 1] = pkrtz_u(e2, e3);                         \
            }                                                                  \
        }                                                                      \
    }                                                                          \
} while (0)

// One pipeline region: V(kt)->regs, stage K(kt+2), phaseA(kt+1) || phaseB(kt).
#define ITER(KT, PFC, PFN) do {                                                \
    half8 vf[2][4];                                                            \
    _Pragma("unroll")                                                          \
    for (int t = 0; t < 2; t++)                                                \
        _Pragma("unroll")                                                      \
        for (int dj = 0; dj < 4; dj++)                                         \
            vf[t][dj] = *reinterpret_cast<const half8*>(                       \
                &Vh[(size_t)(dj * 16 + lh) * SS + (KT) * 64 + t * 32 + quad * 8]); \
    if ((KT) + 2 < 32) STAGE_K((KT) + 2, (KT) & 1);                            \
    if ((KT) + 1 < 32) PHASE_A((KT) + 1, PFN);                                 \
    __builtin_amdgcn_s_setprio(1);                                             \
    _Pragma("unroll")                                                          \
    for (int t = 0; t < 2; t++) {                                              \
        _Pragma("unroll")                                                      \
        for (int i = 0; i < 2; i++) {                                          \
            const u32x4 pu = {PFC[t][i][0], PFC[t][i][1], PFC[t][i][2], PFC[t][i][3]}; \
            const half8 pF = __builtin_bit_cast(half8, pu);                    \
            _Pragma("unroll")                                                  \
            for (int dj = 0; dj < 4; dj++)                                     \
                oacc[i][dj] = __builtin_amdgcn_mfma_f32_16x16x32_f16(          \
                    vf[t][dj], pF, oacc[i][dj], 0, 0, 0);                      \
        }                                                                      \
    }                                                                          \
    __builtin_amdgcn_s_setprio(0);                                             \
    if ((KT) < 31) __syncthreads();                                            \
} while (0)

    // prologue: stage K tiles 0 and 1; fill mask LDS; phaseA(0)
    STAGE_K(0, 0);
    STAGE_K(1, 1);
#pragma unroll
    for (int j = 0; j < 2; j++) {
        const int idx = tid * 8 + j * 4;
        float4 m = *reinterpret_cast<const float4*>(&mk[idx]);
        float4 r;
        r.x = __builtin_fmaf(m.x, L2E, -SH4);
        r.y = __builtin_fmaf(m.y, L2E, -SH4);
        r.z = __builtin_fmaf(m.z, L2E, -SH4);
        r.w = __builtin_fmaf(m.w, L2E, -SH4);
        *reinterpret_cast<float4*>(&lmm[idx]) = r;
    }
    __syncthreads();   // drains K stages 0,1; publishes lmm

    unsigned pfA[2][2][4], pfB[2][2][4];
    PHASE_A(0, pfA);
    __syncthreads();   // all waves done reading lK[0] before ITER(0) overwrites it

    for (int kt = 0; kt < 32; kt += 2) {
        ITER(kt,     pfA, pfB);
        ITER(kt + 1, pfB, pfA);
    }

    // finalize: reduce row-sums across the 4 quads, scale, store (float4)
    float rls[2];
#pragma unroll
    for (int i = 0; i < 2; i++) {
        float l = ls[i];
        l += __shfl_xor(l, 16);
        l += __shfl_xor(l, 32);
        rls[i] = 1.0f / l;
    }
#pragma unroll
    for (int i = 0; i < 2; i++) {
        const int q = q0 + wave * 32 + i * 16 + lh;
#pragma unroll
        for (int dj = 0; dj < 4; dj++) {
            float4 o4;
            o4.x = oacc[i][dj][0] * rls[i];
            o4.y = oacc[i][dj][1] * rls[i];
            o4.z = oacc[i][dj][2] * rls[i];
            o4.w = oacc[i][dj][3] * rls[i];
            *reinterpret_cast<float4*>(
                &out[((size_t)b * SS + q) * HIDD + h * HDD + dj * 16 + quad * 4]) = o4;
        }
    }
#undef ITER
#undef PHASE_A
#undef STAGE_K
}

// ---------------------------------------------------------------- launch
extern "C" void kernel_launch(void* const* d_in, const int* in_sizes, int n_in,
                              void* d_out, int out_size, void* d_ws, size_t ws_size,
                              hipStream_t stream) {
    const float* x    = (const float*)d_in[0];
    const float* mask = (const float*)d_in[1];
    const float* Wq   = (const float*)d_in[2];
    const float* bq   = (const float*)d_in[3];
    const float* Wk   = (const float*)d_in[4];
    const float* bk   = (const float*)d_in[5];
    const float* Wv   = (const float*)d_in[6];
    const float* bv   = (const float*)d_in[7];
    float* out = (float*)d_out;
    (void)in_sizes; (void)n_in; (void)out_size; (void)ws_size;

    unsigned short* ws  = (unsigned short*)d_ws;
    unsigned short* xb  = ws;                                   // 8192*1024
    unsigned short* wb  = xb + (size_t)MM * HIDD;               // 3*1024*1024
    unsigned short* Qb  = wb + (size_t)3 * HIDD * HIDD;         // 8192*1024
    unsigned short* Kb  = Qb + (size_t)MM * HIDD;               // 8192*1024
    _Float16*       Vtb = (_Float16*)(Kb + (size_t)MM * HIDD);  // 8192*1024 f16, transposed

    cvt_all<<<(NX4 + 3 * NW4) / 256, 256, 0, stream>>>(x, Wq, Wk, Wv, xb, wb);

    qkv_gemm<<<dim3(MM / 128, 24), 256, 0, stream>>>(xb, wb, bq, bk, bv, Qb, Kb, Vtb);

    attn_kernel<<<dim3(BB * NHH, SS / 128), 256, 0, stream>>>(Qb, Kb, Vtb, mask, out);
}

// Round 4
// 231.226 us; speedup vs baseline: 1.5946x; 1.5946x over previous
//
#include <hip/hip_runtime.h>
#include <hip/hip_bf16.h>
#include <cstdint>
#include <cstddef>

#define BB   4
#define SS   2048
#define HIDD 1024
#define NHH  16
#define HDD  64
#define MM   (BB*SS)   // 8192
#define L2E  1.4426950408889634f
#define SH4  5.770780163555854f   // 4 * L2E

typedef __bf16    bf16x8 __attribute__((ext_vector_type(8)));
typedef float     f32x4  __attribute__((ext_vector_type(4)));
typedef _Float16  half4  __attribute__((ext_vector_type(4)));
typedef _Float16  half8  __attribute__((ext_vector_type(8)));
typedef _Float16  half2v __attribute__((ext_vector_type(2)));
typedef unsigned  u32x4  __attribute__((ext_vector_type(4)));

__device__ __forceinline__ unsigned short f2b(float f) {
    unsigned u = __builtin_bit_cast(unsigned, f);
    return (unsigned short)((u + 0x7FFFu + ((u >> 16) & 1u)) >> 16);
}

__device__ __forceinline__ half2v pkrtz(float a, float b) {
    return __builtin_bit_cast(half2v, __builtin_amdgcn_cvt_pkrtz(a, b));
}

__device__ __forceinline__ unsigned pkrtz_u(float a, float b) {
    return __builtin_bit_cast(unsigned, __builtin_amdgcn_cvt_pkrtz(a, b));
}

// async global->LDS, 16B per lane. LDS dest must be wave-uniform base + lane*16.
__device__ __forceinline__ void gl_lds16(const void* g, void* l) {
    __builtin_amdgcn_global_load_lds(
        (const __attribute__((address_space(1))) void*)g,
        (__attribute__((address_space(3))) void*)l, 16, 0, 0);
}

// ---------------------------------------------------------------- fp32 -> bf16 (all 4 srcs)
#define NX4 (MM * HIDD / 4)
#define NW4 (HIDD * HIDD / 4)   // 262144 = 2^18
__global__ __launch_bounds__(256) void cvt_all(
    const float* __restrict__ x,  const float* __restrict__ wq,
    const float* __restrict__ wk, const float* __restrict__ wv,
    unsigned short* __restrict__ xb, unsigned short* __restrict__ wb)
{
    int i = blockIdx.x * 256 + threadIdx.x;
    const float* src; unsigned short* dst; int off;
    if (i < NX4) { src = x; dst = xb; off = i; }
    else {
        int j = i - NX4;
        int w = j >> 18;          // 0,1,2
        off = j & (NW4 - 1);
        src = (w == 0) ? wq : (w == 1) ? wk : wv;
        dst = wb + (size_t)w * HIDD * HIDD;
    }
    float4 v = reinterpret_cast<const float4*>(src)[off];
    ushort4 o;
    o.x = f2b(v.x); o.y = f2b(v.y); o.z = f2b(v.z); o.w = f2b(v.w);
    reinterpret_cast<ushort4*>(dst)[off] = o;
}

// ---------------------------------------------------------------- QKV GEMM
// C = x @ W^T + b. grid (64 m-tiles [fastest -> XCD = m%8], 24 = op*8 + n-tile).
// BK=64, XOR-swizzled LDS (row stride 64 elems; 16B group g ^= row&7).
// Operand roles per op:
//   op==2 (V): A = x-tile (rows m), B = W-tile (rows n) -> C rows = s  -> half4 V^T stores
//   op<2 (Q,K): A = W-tile (rows n), B = x-tile (rows m) -> C rows = d -> ushort4 stores
// Q,K written bf16 [B,NH,S,HD]; V written f16 transposed [B,NH,HD,S].
// Q pre-scaled by 0.125*log2(e) (folds softmax scale AND exp->exp2 conversion).
__global__ __launch_bounds__(256, 3) void qkv_gemm(
    const unsigned short* __restrict__ xb,
    const unsigned short* __restrict__ wb,
    const float* __restrict__ bq, const float* __restrict__ bk, const float* __restrict__ bv,
    unsigned short* __restrict__ Qb, unsigned short* __restrict__ Kb,
    _Float16* __restrict__ Vtb)
{
    __shared__ unsigned short lA[128 * 64];  // x-tile, 16 KB
    __shared__ unsigned short lB[128 * 64];  // W-tile, 16 KB

    const int tid  = threadIdx.x;
    const int wave = tid >> 6, lane = tid & 63;
    const int lh   = lane & 15, quad = lane >> 4;
    const int l7   = lh & 7;
    const int m0   = blockIdx.x * 128;
    const int opn  = blockIdx.y;
    const int op   = opn >> 3;            // 0=Q 1=K 2=V
    const int n0   = (opn & 7) * 128;
    const unsigned short* W = wb + (size_t)op * HIDD * HIDD;
    const float* bias = (op == 0) ? bq : (op == 1) ? bk : bv;

    f32x4 acc[4][4];
#pragma unroll
    for (int i = 0; i < 4; i++)
#pragma unroll
        for (int j = 0; j < 4; j++) acc[i][j] = f32x4{0.f, 0.f, 0.f, 0.f};

    const int wm = wave & 1, wn = wave >> 1;
    // A/B operand sources (wave-uniform)
    const unsigned short* srcA = (op == 2) ? lA : lB;
    const unsigned short* srcB = (op == 2) ? lB : lA;
    const int offA = (op == 2) ? wm : wn;
    const int offB = (op == 2) ? wn : wm;

    const int srow = tid >> 3;        // 0..31
    const int sg   = tid & 7;         // 16B group 0..7

    for (int k0 = 0; k0 < HIDD; k0 += 64) {
#pragma unroll
        for (int rr = 0; rr < 4; rr++) {
            const int row = srow + rr * 32;
            const int gcol = k0 + ((sg ^ (row & 7)) << 3);
            gl_lds16(&xb[(size_t)(m0 + row) * HIDD + gcol], &lA[row * 64 + sg * 8]);
            gl_lds16(&W [(size_t)(n0 + row) * HIDD + gcol], &lB[row * 64 + sg * 8]);
        }
        __syncthreads();

#pragma unroll
        for (int kk = 0; kk < 2; kk++) {
            bf16x8 aF[4], bF[4];
#pragma unroll
            for (int i = 0; i < 4; i++) {
                const int row = offA * 64 + i * 16 + lh;
                aF[i] = *reinterpret_cast<const bf16x8*>(
                    &srcA[row * 64 + (((kk * 4 + quad) ^ l7) << 3)]);
            }
#pragma unroll
            for (int j = 0; j < 4; j++) {
                const int row = offB * 64 + j * 16 + lh;
                bF[j] = *reinterpret_cast<const bf16x8*>(
                    &srcB[row * 64 + (((kk * 4 + quad) ^ l7) << 3)]);
            }
#pragma unroll
            for (int i = 0; i < 4; i++)
#pragma unroll
                for (int j = 0; j < 4; j++)
                    acc[i][j] = __builtin_amdgcn_mfma_f32_16x16x32_bf16(aF[i], bF[j], acc[i][j], 0, 0, 0);
        }
        __syncthreads();
    }

    // epilogue: C/D layout col = lane&15, row = quad*4 + reg
    if (op == 2) {
        // rows = m (s), cols = n (d): V^T[d][s], 4 consecutive s per lane -> half4
#pragma unroll
        for (int j = 0; j < 4; j++) {
            const int n = n0 + offB * 64 + j * 16 + lh;
            const float bvv = bias[n];
            const int h = n >> 6, d = n & 63;
#pragma unroll
            for (int i = 0; i < 4; i++) {
                const int mrow = m0 + offA * 64 + i * 16 + quad * 4;
                const int b_ = mrow >> 11, s_ = mrow & 2047;
                half2v h01 = pkrtz(acc[i][j][0] + bvv, acc[i][j][1] + bvv);
                half2v h23 = pkrtz(acc[i][j][2] + bvv, acc[i][j][3] + bvv);
                half4 hv; hv[0] = h01[0]; hv[1] = h01[1]; hv[2] = h23[0]; hv[3] = h23[1];
                size_t a = ((size_t)(b_ * NHH + h) * HDD + d) * SS + s_;
                *reinterpret_cast<half4*>(&Vtb[a]) = hv;
            }
        }
    } else {
        // rows = n (d), cols = m (s): Q/K[s][d], 4 consecutive d per lane -> ushort4
        const float qs = (op == 0) ? (0.125f * L2E) : 1.0f;
        unsigned short* dst = (op == 0) ? Qb : Kb;
#pragma unroll
        for (int i = 0; i < 4; i++) {
            const int nb = n0 + offA * 64 + i * 16 + quad * 4;
            const float4 bb = *reinterpret_cast<const float4*>(&bias[nb]);
            const int h = nb >> 6, d = nb & 63;
#pragma unroll
            for (int j = 0; j < 4; j++) {
                const int m = m0 + offB * 64 + j * 16 + lh;
                const int b_ = m >> 11, s_ = m & 2047;
                ushort4 o;
                o.x = f2b((acc[i][j][0] + bb.x) * qs);
                o.y = f2b((acc[i][j][1] + bb.y) * qs);
                o.z = f2b((acc[i][j][2] + bb.z) * qs);
                o.w = f2b((acc[i][j][3] + bb.w) * qs);
                *reinterpret_cast<ushort4*>(
                    &dst[((size_t)(b_ * NHH + h) * SS + s_) * HDD + d]) = o;
            }
        }
    }
}

// ---------------------------------------------------------------- flash attention
// grid (64 = b*NH+h [fastest -> all q-tiles of a head on one XCD], 16 q-tiles).
// 256 threads, q-tile 128 (32 q per wave). kt tile 64 keys, double-buffered.
// S^T = K*Q^T with PERMUTED key rows (see R1/R2 comments): the QK C-output
// concatenated over a=0/1 is exactly the K=32 16x16x32 f16 PV B-operand.
// R4 (revert R3, half-step): HALF-TILE PV CARRY. The second half-tile's packed
// P (pfc, 8 VGPR) and its V fragment (vfc, 16 VGPR, ds_read BEFORE the barrier
// -> race-free vs next STAGE) are carried across the per-kt __syncthreads, and
// its 10 pure-register PV MFMAs issue IMMEDIATELY after the barrier - filling
// the post-barrier LDS-latency ramp the compiler cannot bridge itself (it may
// not hoist LDS reads across the barrier; registers it can't know are safe).
// V stays in LDS (R3's per-wave global V = 4x L2 traffic + spills = 2.8x slower).
// Iteration 0 consumes a zero carry (ones*0 and 0*0 are exact no-ops); one
// epilogue PV after the loop. A(t1)/LOADV(t1) write carry regs directly (no copies).
__global__ __launch_bounds__(256, 4) void attn_kernel(
    const unsigned short* __restrict__ Qb,
    const unsigned short* __restrict__ Kb,
    const _Float16* __restrict__ Vtb,
    const float* __restrict__ mask,
    float* __restrict__ out)
{
    __shared__ unsigned short lK[2][64 * 64];  // keys x d, swizzled (bits 0,1,3); 8 KB each
    __shared__ _Float16      lV[2][64 * 64];   // d x keys, swizzled (bits 0,1,2); 8 KB each
    __shared__ float         lmm[SS];          // mask*L2E - SH4, per key; 8 KB

    const int tid  = threadIdx.x;
    const int wave = tid >> 6, lane = tid & 63;
    const int lh   = lane & 15, quad = lane >> 4;
    const int l7   = lh & 7;
    const int bh = blockIdx.x, qt = blockIdx.y;
    const int b = bh >> 4, h = bh & 15;
    const unsigned short* Qh = Qb  + (size_t)bh * SS * HDD;
    const unsigned short* Kh = Kb  + (size_t)bh * SS * HDD;
    const _Float16*       Vh = Vtb + (size_t)bh * HDD * SS;
    const float* mk = mask + (size_t)b * SS;
    const int q0 = qt * 128;

    // Q fragments (B-operand): q = q0 + wave*32 + i*16 + lh, d = kk*32 + quad*8
    bf16x8 qF[2][2];
#pragma unroll
    for (int i = 0; i < 2; i++)
#pragma unroll
        for (int kk = 0; kk < 2; kk++)
            qF[i][kk] = *reinterpret_cast<const bf16x8*>(
                &Qh[(size_t)(q0 + wave * 32 + i * 16 + lh) * HDD + kk * 32 + quad * 8]);

    f32x4 oacc[2][4];
#pragma unroll
    for (int i = 0; i < 2; i++)
#pragma unroll
        for (int dj = 0; dj < 4; dj++) oacc[i][dj] = f32x4{0.f, 0.f, 0.f, 0.f};
    f32x4 osum[2] = {f32x4{0.f, 0.f, 0.f, 0.f}, f32x4{0.f, 0.f, 0.f, 0.f}};

    const u32x4 one_u = {0x3C003C00u, 0x3C003C00u, 0x3C003C00u, 0x3C003C00u};
    const half8 vone  = __builtin_bit_cast(half8, one_u);

    const int srow = tid >> 3;        // 0..31
    const int sg   = tid & 7;

#define STAGE(KT, BUF) do {                                                     \
    const int kb_ = (KT) * 64;                                                  \
    _Pragma("unroll")                                                           \
    for (int rr = 0; rr < 2; rr++) {                                            \
        const int row = srow + rr * 32;                                         \
        const int swk = ((sg ^ ((row & 3) | ((row >> 1) & 4))) << 3);           \
        const int swv = ((sg ^ (row & 7)) << 3);                                \
        gl_lds16(&Kh[(size_t)(kb_ + row) * HDD + swk], &lK[BUF][row * 64 + sg * 8]); \
        gl_lds16(&Vh[(size_t)row * SS + kb_ + swv],    &lV[BUF][row * 64 + sg * 8]); \
    }                                                                           \
} while (0)

// QK scores + exp2 + pack for half-tile T (0/1) of tile kt -> PF[2][4] words
#define A_HALF(T, PF) do {                                                     \
    _Pragma("unroll")                                                          \
    for (int a = 0; a < 2; a++) {                                              \
        const int key = (T) * 32 + ((lh & 12) << 1) + (a << 2) + (lh & 3);     \
        const int krow = key * 64;                                             \
        bf16x8 kf0 = *reinterpret_cast<const bf16x8*>(                         \
            &lK[buf][krow + ((quad ^ l7) << 3)]);                              \
        bf16x8 kf1 = *reinterpret_cast<const bf16x8*>(                         \
            &lK[buf][krow + (((4 + quad) ^ l7) << 3)]);                        \
        const f32x4 mm = *reinterpret_cast<const f32x4*>(                      \
            &lmm[kb + (T) * 32 + quad * 8 + a * 4]);                           \
        _Pragma("unroll")                                                      \
        for (int i = 0; i < 2; i++) {                                          \
            f32x4 s = __builtin_amdgcn_mfma_f32_16x16x32_bf16(kf0, qF[i][0], mm, 0, 0, 0); \
            s = __builtin_amdgcn_mfma_f32_16x16x32_bf16(kf1, qF[i][1], s, 0, 0, 0);        \
            PF[i][a * 2 + 0] = pkrtz_u(__builtin_amdgcn_exp2f(s[0]),           \
                                       __builtin_amdgcn_exp2f(s[1]));          \
            PF[i][a * 2 + 1] = pkrtz_u(__builtin_amdgcn_exp2f(s[2]),           \
                                       __builtin_amdgcn_exp2f(s[3]));          \
        }                                                                      \
    }                                                                          \
} while (0)

// V fragment for half-tile T of tile kt (4 conflict-free ds_read_b128)
#define LOADV(T, VF) do {                                                      \
    _Pragma("unroll")                                                          \
    for (int dj = 0; dj < 4; dj++)                                             \
        VF[dj] = *reinterpret_cast<const half8*>(                              \
            &lV[buf][(dj * 16 + lh) * 64 + ((((T) * 4 + quad) ^ l7) << 3)]);   \
} while (0)

// PV + row-sum for one half-tile: 10 pure-register K=32 f16 MFMAs
#define PV_HALF(PF, VF) do {                                                   \
    __builtin_amdgcn_s_setprio(1);                                             \
    _Pragma("unroll")                                                          \
    for (int i = 0; i < 2; i++) {                                              \
        const u32x4 pu = {PF[i][0], PF[i][1], PF[i][2], PF[i][3]};             \
        const half8 pF = __builtin_bit_cast(half8, pu);                        \
        osum[i] = __builtin_amdgcn_mfma_f32_16x16x32_f16(vone, pF, osum[i], 0, 0, 0); \
        _Pragma("unroll")                                                      \
        for (int dj = 0; dj < 4; dj++)                                         \
            oacc[i][dj] = __builtin_amdgcn_mfma_f32_16x16x32_f16(              \
                VF[dj], pF, oacc[i][dj], 0, 0, 0);                             \
    }                                                                          \
    __builtin_amdgcn_s_setprio(0);                                             \
} while (0)

    // carried half-tile state (consumed at top of body, rewritten at bottom)
    unsigned pfc[2][4];
    half8    vfc[4];
#pragma unroll
    for (int i = 0; i < 2; i++)
#pragma unroll
        for (int w = 0; w < 4; w++) pfc[i][w] = 0u;
#pragma unroll
    for (int dj = 0; dj < 4; dj++)
        vfc[dj] = __builtin_bit_cast(half8, u32x4{0u, 0u, 0u, 0u});

    STAGE(0, 0);

    // one-time: mask -> exp2-domain additive term, staged in LDS
#pragma unroll
    for (int j = 0; j < 2; j++) {
        const int idx = tid * 8 + j * 4;
        float4 m = *reinterpret_cast<const float4*>(&mk[idx]);
        float4 r;
        r.x = __builtin_fmaf(m.x, L2E, -SH4);
        r.y = __builtin_fmaf(m.y, L2E, -SH4);
        r.z = __builtin_fmaf(m.z, L2E, -SH4);
        r.w = __builtin_fmaf(m.w, L2E, -SH4);
        *reinterpret_cast<float4*>(&lmm[idx]) = r;
    }
    __syncthreads();

    for (int kt = 0; kt < SS / 64; kt++) {
        if (kt < SS / 64 - 1) STAGE(kt + 1, (kt + 1) & 1);
        const int buf = kt & 1;
        const int kb = kt * 64;

        // PV of the carried half-tile: register-only, fills post-barrier ramp
        PV_HALF(pfc, vfc);

        // half-tile 0 of this kt
        unsigned pf0[2][4];
        A_HALF(0, pf0);
        half8 vf0[4];
        LOADV(0, vf0);
        PV_HALF(pf0, vf0);

        // half-tile 1 -> carry (ds_reads complete before the barrier -> safe
        // vs STAGE(kt+2) overwriting this buffer next iteration)
        A_HALF(1, pfc);
        LOADV(1, vfc);

        if (kt < SS / 64 - 1) __syncthreads();
    }
    PV_HALF(pfc, vfc);   // last carried half-tile (kt=31, t=1)

    // finalize: osum[i][0] already holds the full row sum for q = lh (all lanes)
#pragma unroll
    for (int i = 0; i < 2; i++) {
        const float rls = 1.0f / osum[i][0];
        const int q = q0 + wave * 32 + i * 16 + lh;
#pragma unroll
        for (int dj = 0; dj < 4; dj++) {
            float4 o4;
            o4.x = oacc[i][dj][0] * rls;
            o4.y = oacc[i][dj][1] * rls;
            o4.z = oacc[i][dj][2] * rls;
            o4.w = oacc[i][dj][3] * rls;
            *reinterpret_cast<float4*>(
                &out[((size_t)b * SS + q) * HIDD + h * HDD + dj * 16 + quad * 4]) = o4;
        }
    }
#undef PV_HALF
#undef LOADV
#undef A_HALF
#undef STAGE
}

// ---------------------------------------------------------------- launch
extern "C" void kernel_launch(void* const* d_in, const int* in_sizes, int n_in,
                              void* d_out, int out_size, void* d_ws, size_t ws_size,
                              hipStream_t stream) {
    const float* x    = (const float*)d_in[0];
    const float* mask = (const float*)d_in[1];
    const float* Wq   = (const float*)d_in[2];
    const float* bq   = (const float*)d_in[3];
    const float* Wk   = (const float*)d_in[4];
    const float* bk   = (const float*)d_in[5];
    const float* Wv   = (const float*)d_in[6];
    const float* bv   = (const float*)d_in[7];
    float* out = (float*)d_out;
    (void)in_sizes; (void)n_in; (void)out_size; (void)ws_size;

    unsigned short* ws  = (unsigned short*)d_ws;
    unsigned short* xb  = ws;                                   // 8192*1024
    unsigned short* wb  = xb + (size_t)MM * HIDD;               // 3*1024*1024
    unsigned short* Qb  = wb + (size_t)3 * HIDD * HIDD;         // 8192*1024
    unsigned short* Kb  = Qb + (size_t)MM * HIDD;               // 8192*1024
    _Float16*       Vtb = (_Float16*)(Kb + (size_t)MM * HIDD);  // 8192*1024 f16, transposed

    cvt_all<<<(NX4 + 3 * NW4) / 256, 256, 0, stream>>>(x, Wq, Wk, Wv, xb, wb);

    qkv_gemm<<<dim3(MM / 128, 24), 256, 0, stream>>>(xb, wb, bq, bk, bv, Qb, Kb, Vtb);

    attn_kernel<<<dim3(BB * NHH, SS / 128), 256, 0, stream>>>(Qb, Kb, Vtb, mask, out);
}